// Round 1
// baseline (419.822 us; speedup 1.0000x reference)
//
#include <hip/hip_runtime.h>
#include <math.h>

#define NN 8192
#define DD 512
#define HH 256
#define EE 262144
#define ALPHAC 0.1520f
#define BETAC  0.7900f

// ---------- CSR build ----------
__global__ __launch_bounds__(256) void zero_cnt_kernel(int* __restrict__ cnt) {
  cnt[blockIdx.x * 256 + threadIdx.x] = 0;
}

__global__ __launch_bounds__(256) void count_edges_kernel(const int* __restrict__ dst,
                                                          int* __restrict__ cnt) {
  int e = blockIdx.x * 256 + threadIdx.x;
  atomicAdd(&cnt[dst[e]], 1);
}

// single block, 256 threads, 32 nodes/thread: exclusive scan -> row_ptr, cursor, dinv
__global__ __launch_bounds__(256) void scan_build_kernel(const int* __restrict__ cnt,
    int* __restrict__ row_ptr, int* __restrict__ cursor, float* __restrict__ dinv) {
  int t = threadIdx.x;
  int base = t * 32;
  int local[32];
  int s = 0;
#pragma unroll
  for (int k = 0; k < 32; ++k) { local[k] = cnt[base + k]; s += local[k]; }
  int inc = s;
#pragma unroll
  for (int off = 1; off < 64; off <<= 1) {
    int v = __shfl_up(inc, off, 64);
    if ((t & 63) >= off) inc += v;
  }
  __shared__ int wsum[4];
  int lane = t & 63, wid = t >> 6;
  if (lane == 63) wsum[wid] = inc;
  __syncthreads();
  int woff = 0;
  for (int w = 0; w < wid; ++w) woff += wsum[w];
  int run = woff + inc - s;  // exclusive prefix for this thread's chunk
#pragma unroll
  for (int k = 0; k < 32; ++k) {
    row_ptr[base + k] = run;
    cursor[base + k] = run;
    dinv[base + k] = rsqrtf((float)cnt[base + k] + 1.0f);
    run += local[k];
  }
  if (t == 255) row_ptr[NN] = run;  // == EE
}

__global__ __launch_bounds__(256) void scatter_edges_kernel(const int* __restrict__ src,
    const int* __restrict__ dst, int* __restrict__ cursor,
    const float* __restrict__ dinv, int* __restrict__ srcs, float* __restrict__ norms) {
  int e = blockIdx.x * 256 + threadIdx.x;
  int s = src[e], d = dst[e];
  int pos = atomicAdd(&cursor[d], 1);
  srcs[pos] = s;
  norms[pos] = dinv[s];
}

// ---------- GEMM: t1[NN,HH] = features[NN,DD] @ W1[DD,HH] (fp32, vector ALU) ----------
__global__ __launch_bounds__(256) void gemm1_kernel(const float* __restrict__ A,
    const float* __restrict__ B, float* __restrict__ C) {
  __shared__ float As[16][65];  // [k][m], +1 pad
  __shared__ float Bs[16][64];  // [k][n]
  int t = threadIdx.x;
  int tx = t & 15, ty = t >> 4;
  int m0 = blockIdx.y * 64, n0 = blockIdx.x * 64;
  int arow = t >> 2;
  int acol4 = (t & 3) * 4;
  int brow = t >> 4;
  int bcol4 = (t & 15) * 4;
  float acc[4][4] = {};
  for (int k0 = 0; k0 < DD; k0 += 16) {
    float4 av = *(const float4*)&A[(size_t)(m0 + arow) * DD + k0 + acol4];
    float4 bv = *(const float4*)&B[(size_t)(k0 + brow) * HH + n0 + bcol4];
    As[acol4 + 0][arow] = av.x;
    As[acol4 + 1][arow] = av.y;
    As[acol4 + 2][arow] = av.z;
    As[acol4 + 3][arow] = av.w;
    *(float4*)&Bs[brow][bcol4] = bv;
    __syncthreads();
#pragma unroll
    for (int k = 0; k < 16; ++k) {
      float a[4], b[4];
#pragma unroll
      for (int i = 0; i < 4; ++i) a[i] = As[k][ty * 4 + i];
#pragma unroll
      for (int j = 0; j < 4; ++j) b[j] = Bs[k][tx * 4 + j];
#pragma unroll
      for (int i = 0; i < 4; ++i)
#pragma unroll
        for (int j = 0; j < 4; ++j) acc[i][j] = fmaf(a[i], b[j], acc[i][j]);
    }
    __syncthreads();
  }
#pragma unroll
  for (int i = 0; i < 4; ++i) {
    float4 o = make_float4(acc[i][0], acc[i][1], acc[i][2], acc[i][3]);
    *(float4*)&C[(size_t)(m0 + ty * 4 + i) * HH + n0 + tx * 4] = o;
  }
}

// ---------- layer1: agg = Â t1 ; h = relu(agg + b1) ; t2 = h @ W2 (fused) ----------
// one block (256 threads) per node; thread tid owns feature dim tid
__global__ __launch_bounds__(256) void layer1_kernel(const float* __restrict__ t1,
    const int* __restrict__ row_ptr, const int* __restrict__ srcs,
    const float* __restrict__ norms, const float* __restrict__ dinv,
    const float* __restrict__ b1, const float* __restrict__ W2,
    float* __restrict__ t2) {
  int i = blockIdx.x;
  int tid = threadIdx.x;
  float di = dinv[i];
  int beg = row_ptr[i], end = row_ptr[i + 1];
  float acc = 0.f;
  for (int e = beg; e < end; ++e) {
    int s = srcs[e];
    float ns = norms[e];
    acc += ns * t1[(size_t)s * HH + tid];
  }
  acc = di * acc + di * di * t1[(size_t)i * HH + tid];
  float h = fmaxf(acc + b1[tid], 0.f);
  float p0 = h * W2[tid * 2 + 0];
  float p1 = h * W2[tid * 2 + 1];
#pragma unroll
  for (int off = 32; off > 0; off >>= 1) {
    p0 += __shfl_down(p0, off, 64);
    p1 += __shfl_down(p1, off, 64);
  }
  __shared__ float red[8];
  int lane = tid & 63, wid = tid >> 6;
  if (lane == 0) { red[wid * 2] = p0; red[wid * 2 + 1] = p1; }
  __syncthreads();
  if (tid == 0) {
    t2[i * 2 + 0] = red[0] + red[2] + red[4] + red[6];
    t2[i * 2 + 1] = red[1] + red[3] + red[5] + red[7];
  }
}

// ---------- layer2: emb = Â t2 + b2 ; sq = |emb|^2 ----------
// one wave per node, 4 waves/block
__global__ __launch_bounds__(256) void layer2_kernel(const float* __restrict__ t2,
    const int* __restrict__ row_ptr, const int* __restrict__ srcs,
    const float* __restrict__ norms, const float* __restrict__ dinv,
    const float* __restrict__ b2, float* __restrict__ emb, float* __restrict__ sq) {
  int wid = threadIdx.x >> 6;
  int lane = threadIdx.x & 63;
  int i = blockIdx.x * 4 + wid;
  float di = dinv[i];
  int beg = row_ptr[i], end = row_ptr[i + 1];
  float a0 = 0.f, a1 = 0.f;
  for (int e = beg + lane; e < end; e += 64) {
    int s = srcs[e];
    float ns = norms[e];
    a0 += ns * t2[2 * s + 0];
    a1 += ns * t2[2 * s + 1];
  }
#pragma unroll
  for (int off = 32; off > 0; off >>= 1) {
    a0 += __shfl_down(a0, off, 64);
    a1 += __shfl_down(a1, off, 64);
  }
  if (lane == 0) {
    float e0 = di * a0 + di * di * t2[2 * i + 0] + b2[0];
    float e1 = di * a1 + di * di * t2[2 * i + 1] + b2[1];
    emb[2 * i + 0] = e0;
    emb[2 * i + 1] = e1;
    sq[i] = e0 * e0 + e1 * e1;
  }
}

// ---------- q matrix: q[i][j] = 1/(1 + alpha * d2^beta) ----------
// block: 1024 j (4/thread float4), loop 32 i
__global__ __launch_bounds__(256) void q_kernel(const float* __restrict__ emb,
    const float* __restrict__ sq, float* __restrict__ q) {
  int t = threadIdx.x;
  int j0 = blockIdx.x * 1024 + t * 4;
  int i0 = blockIdx.y * 32;
  float ex[4], ey[4], sj[4];
#pragma unroll
  for (int jj = 0; jj < 4; ++jj) {
    ex[jj] = emb[2 * (j0 + jj) + 0];
    ey[jj] = emb[2 * (j0 + jj) + 1];
    sj[jj] = sq[j0 + jj];
  }
  for (int ii = 0; ii < 32; ++ii) {
    int i = i0 + ii;
    float xi = emb[2 * i + 0], yi = emb[2 * i + 1], si = sq[i];
    float out4[4];
#pragma unroll
    for (int jj = 0; jj < 4; ++jj) {
      float d2 = si + sj[jj] - 2.f * (xi * ex[jj] + yi * ey[jj]);
      d2 = fmaxf(d2, 0.f);
      float pw = __expf(BETAC * __logf(d2));         // d2^beta (fast path)
      float den = fmaf(ALPHAC, pw, 1.f);
      float qv = __builtin_amdgcn_rcpf(den);         // den >= 1, ~1 ulp
      out4[jj] = (d2 > 0.f) ? qv : 1.f;
    }
    float4 r = make_float4(out4[0], out4[1], out4[2], out4[3]);
    *(float4*)&q[(size_t)i * NN + j0] = r;
  }
}

extern "C" void kernel_launch(void* const* d_in, const int* in_sizes, int n_in,
                              void* d_out, int out_size, void* d_ws, size_t ws_size,
                              hipStream_t stream) {
  const float* features = (const float*)d_in[0];
  const int* edge_index = (const int*)d_in[1];
  const float* W1 = (const float*)d_in[2];
  const float* b1 = (const float*)d_in[3];
  const float* W2 = (const float*)d_in[4];
  const float* b2 = (const float*)d_in[5];
  float* out = (float*)d_out;

  const int* src = edge_index;       // edge_index[0]
  const int* dst = edge_index + EE;  // edge_index[1]

  // workspace layout (~10.7 MB)
  int* cnt = (int*)d_ws;                 // NN
  int* row_ptr = cnt + NN;               // NN+1 (padded to 8448)
  int* cursor = row_ptr + 8448;          // NN
  int* srcs = cursor + NN;               // EE
  float* norms = (float*)(srcs + EE);    // EE
  float* dinv = norms + EE;              // NN
  float* sqv = dinv + NN;                // NN
  float* t2 = sqv + NN;                  // 2*NN
  float* t1 = t2 + 2 * NN;               // NN*HH

  float* emb = out;              // [NN,2]
  float* qout = out + 2 * NN;    // [NN,NN]

  zero_cnt_kernel<<<NN / 256, 256, 0, stream>>>(cnt);
  count_edges_kernel<<<EE / 256, 256, 0, stream>>>(dst, cnt);
  scan_build_kernel<<<1, 256, 0, stream>>>(cnt, row_ptr, cursor, dinv);
  scatter_edges_kernel<<<EE / 256, 256, 0, stream>>>(src, dst, cursor, dinv, srcs, norms);
  gemm1_kernel<<<dim3(HH / 64, NN / 64), 256, 0, stream>>>(features, W1, t1);
  layer1_kernel<<<NN, 256, 0, stream>>>(t1, row_ptr, srcs, norms, dinv, b1, W2, t2);
  layer2_kernel<<<NN / 4, 256, 0, stream>>>(t2, row_ptr, srcs, norms, dinv, b2, emb, sqv);
  q_kernel<<<dim3(NN / 1024, NN / 32), 256, 0, stream>>>(emb, sqv, qout);
}

// Round 3
// 382.899 us; speedup vs baseline: 1.0964x; 1.0964x over previous
//
#include <hip/hip_runtime.h>
#include <math.h>

#define NN 8192
#define DD 512
#define HH 256
#define EE 262144
#define ALPHAC 0.1520f
#define BETAC  0.7900f

typedef float floatx4 __attribute__((ext_vector_type(4)));

// ---------- CSR build ----------
__global__ __launch_bounds__(256) void zero_cnt_kernel(int* __restrict__ cnt) {
  cnt[blockIdx.x * 256 + threadIdx.x] = 0;
}

__global__ __launch_bounds__(256) void count_edges_kernel(const int* __restrict__ dst,
                                                          int* __restrict__ cnt) {
  int e = blockIdx.x * 256 + threadIdx.x;
  atomicAdd(&cnt[dst[e]], 1);
}

// single block, 256 threads, 32 nodes/thread: exclusive scan -> row_ptr, cursor, dinv
__global__ __launch_bounds__(256) void scan_build_kernel(const int* __restrict__ cnt,
    int* __restrict__ row_ptr, int* __restrict__ cursor, float* __restrict__ dinv) {
  int t = threadIdx.x;
  int base = t * 32;
  int local[32];
  int s = 0;
#pragma unroll
  for (int k = 0; k < 32; ++k) { local[k] = cnt[base + k]; s += local[k]; }
  int inc = s;
#pragma unroll
  for (int off = 1; off < 64; off <<= 1) {
    int v = __shfl_up(inc, off, 64);
    if ((t & 63) >= off) inc += v;
  }
  __shared__ int wsum[4];
  int lane = t & 63, wid = t >> 6;
  if (lane == 63) wsum[wid] = inc;
  __syncthreads();
  int woff = 0;
  for (int w = 0; w < wid; ++w) woff += wsum[w];
  int run = woff + inc - s;  // exclusive prefix for this thread's chunk
#pragma unroll
  for (int k = 0; k < 32; ++k) {
    row_ptr[base + k] = run;
    cursor[base + k] = run;
    dinv[base + k] = rsqrtf((float)cnt[base + k] + 1.0f);
    run += local[k];
  }
  if (t == 255) row_ptr[NN] = run;  // == EE
}

__global__ __launch_bounds__(256) void scatter_edges_kernel(const int* __restrict__ src,
    const int* __restrict__ dst, int* __restrict__ cursor,
    const float* __restrict__ dinv, int* __restrict__ srcs, float* __restrict__ norms) {
  int e = blockIdx.x * 256 + threadIdx.x;
  int s = src[e], d = dst[e];
  int pos = atomicAdd(&cursor[d], 1);
  srcs[pos] = s;
  norms[pos] = dinv[s];
}

// ---------- GEMM: t1[NN,HH] = features[NN,DD] @ W1[DD,HH] ----------
// 128x64 tile, 8x4 microtile, BK=16, reg-prefetch pipeline, b128 LDS frags.
#define BM 128
#define BN 64
#define BK 16
__global__ __launch_bounds__(256) void gemm1_kernel(const float* __restrict__ A,
    const float* __restrict__ B, float* __restrict__ C) {
  __shared__ float As[BK][BM + 4];  // stride 132 floats (16B-aligned rows)
  __shared__ float Bs[BK][BN + 4];  // stride 68 floats
  int t = threadIdx.x;
  int tx = t & 15;   // n-dir: 16 cols of 4
  int ty = t >> 4;   // m-dir: 16 rows of 8
  int m0 = blockIdx.y * BM, n0 = blockIdx.x * BN;
  // A staging: 128 rows x 16 k = 512 float4; 2 per thread
  int arow = t >> 1;            // 0..127
  int acol = (t & 1) * 8;       // 0 or 8
  // B staging: 16 rows x 64 = 256 float4; 1 per thread
  int brow = t >> 4;            // 0..15
  int bcol = (t & 15) * 4;

  const float* aptr0 = &A[(size_t)(m0 + arow) * DD + acol];
  const float* bptr = &B[(size_t)brow * HH + n0 + bcol];

  float acc[8][4] = {};
  float4 a0v = *(const float4*)(aptr0 + 0);
  float4 a1v = *(const float4*)(aptr0 + 4);
  float4 bv = *(const float4*)(bptr);

  for (int k0 = 0; k0 < DD; k0 += BK) {
    As[acol + 0][arow] = a0v.x; As[acol + 1][arow] = a0v.y;
    As[acol + 2][arow] = a0v.z; As[acol + 3][arow] = a0v.w;
    As[acol + 4][arow] = a1v.x; As[acol + 5][arow] = a1v.y;
    As[acol + 6][arow] = a1v.z; As[acol + 7][arow] = a1v.w;
    *(float4*)&Bs[brow][bcol] = bv;
    __syncthreads();
    if (k0 + BK < DD) {  // prefetch next tile while computing this one
      a0v = *(const float4*)(aptr0 + k0 + BK + 0);
      a1v = *(const float4*)(aptr0 + k0 + BK + 4);
      bv = *(const float4*)(bptr + (size_t)(k0 + BK) * HH);
    }
#pragma unroll
    for (int k = 0; k < BK; ++k) {
      float4 xa = *(const float4*)&As[k][ty * 8];
      float4 xb = *(const float4*)&As[k][ty * 8 + 4];
      float4 bb = *(const float4*)&Bs[k][tx * 4];
      float am[8] = {xa.x, xa.y, xa.z, xa.w, xb.x, xb.y, xb.z, xb.w};
      float bn[4] = {bb.x, bb.y, bb.z, bb.w};
#pragma unroll
      for (int i = 0; i < 8; ++i)
#pragma unroll
        for (int j = 0; j < 4; ++j) acc[i][j] = fmaf(am[i], bn[j], acc[i][j]);
    }
    __syncthreads();
  }
#pragma unroll
  for (int i = 0; i < 8; ++i) {
    float4 o = make_float4(acc[i][0], acc[i][1], acc[i][2], acc[i][3]);
    *(float4*)&C[(size_t)(m0 + ty * 8 + i) * HH + n0 + tx * 4] = o;
  }
}

// ---------- layer1: agg = A_hat t1 ; h = relu(agg + b1) ; t2 = h @ W2 (fused) ----------
// one wave per node (4 nodes/block); lane owns 4 feature dims (float4)
__global__ __launch_bounds__(256) void layer1_kernel(const float* __restrict__ t1,
    const int* __restrict__ row_ptr, const int* __restrict__ srcs,
    const float* __restrict__ norms, const float* __restrict__ dinv,
    const float* __restrict__ b1, const float* __restrict__ W2,
    float* __restrict__ t2) {
  int wid = threadIdx.x >> 6;
  int lane = threadIdx.x & 63;
  int i = blockIdx.x * 4 + wid;
  float di = dinv[i];
  int beg = row_ptr[i], end = row_ptr[i + 1];
  float4 acc = make_float4(0.f, 0.f, 0.f, 0.f);
  for (int base = beg; base < end; base += 64) {
    int cnt = end - base;
    if (cnt > 64) cnt = 64;
    int s_reg = 0;
    float n_reg = 0.f;
    if (lane < cnt) { s_reg = srcs[base + lane]; n_reg = norms[base + lane]; }
    int c = 0;
    for (; c + 4 <= cnt; c += 4) {
      int s0 = __shfl(s_reg, c, 64), s1 = __shfl(s_reg, c + 1, 64);
      int s2 = __shfl(s_reg, c + 2, 64), s3 = __shfl(s_reg, c + 3, 64);
      float q0 = __shfl(n_reg, c, 64), q1 = __shfl(n_reg, c + 1, 64);
      float q2 = __shfl(n_reg, c + 2, 64), q3 = __shfl(n_reg, c + 3, 64);
      float4 v0 = *(const float4*)&t1[(size_t)s0 * HH + lane * 4];
      float4 v1 = *(const float4*)&t1[(size_t)s1 * HH + lane * 4];
      float4 v2 = *(const float4*)&t1[(size_t)s2 * HH + lane * 4];
      float4 v3 = *(const float4*)&t1[(size_t)s3 * HH + lane * 4];
      acc.x = fmaf(q0, v0.x, fmaf(q1, v1.x, fmaf(q2, v2.x, fmaf(q3, v3.x, acc.x))));
      acc.y = fmaf(q0, v0.y, fmaf(q1, v1.y, fmaf(q2, v2.y, fmaf(q3, v3.y, acc.y))));
      acc.z = fmaf(q0, v0.z, fmaf(q1, v1.z, fmaf(q2, v2.z, fmaf(q3, v3.z, acc.z))));
      acc.w = fmaf(q0, v0.w, fmaf(q1, v1.w, fmaf(q2, v2.w, fmaf(q3, v3.w, acc.w))));
    }
    for (; c < cnt; ++c) {
      int s = __shfl(s_reg, c, 64);
      float qn = __shfl(n_reg, c, 64);
      float4 v = *(const float4*)&t1[(size_t)s * HH + lane * 4];
      acc.x = fmaf(qn, v.x, acc.x);
      acc.y = fmaf(qn, v.y, acc.y);
      acc.z = fmaf(qn, v.z, acc.z);
      acc.w = fmaf(qn, v.w, acc.w);
    }
  }
  float4 self = *(const float4*)&t1[(size_t)i * HH + lane * 4];
  float4 bv = *(const float4*)&b1[lane * 4];
  float dd = di * di;
  float4 h;
  h.x = fmaxf(fmaf(di, acc.x, fmaf(dd, self.x, bv.x)), 0.f);
  h.y = fmaxf(fmaf(di, acc.y, fmaf(dd, self.y, bv.y)), 0.f);
  h.z = fmaxf(fmaf(di, acc.z, fmaf(dd, self.z, bv.z)), 0.f);
  h.w = fmaxf(fmaf(di, acc.w, fmaf(dd, self.w, bv.w)), 0.f);
  // W2 rows lane*4..lane*4+3, cols 0..1 -> 8 consecutive floats
  float4 w0 = *(const float4*)&W2[lane * 8];
  float4 w1 = *(const float4*)&W2[lane * 8 + 4];
  float p0 = h.x * w0.x + h.y * w0.z + h.z * w1.x + h.w * w1.z;
  float p1 = h.x * w0.y + h.y * w0.w + h.z * w1.y + h.w * w1.w;
#pragma unroll
  for (int off = 32; off > 0; off >>= 1) {
    p0 += __shfl_down(p0, off, 64);
    p1 += __shfl_down(p1, off, 64);
  }
  if (lane == 0) {
    t2[i * 2 + 0] = p0;
    t2[i * 2 + 1] = p1;
  }
}

// ---------- layer2: emb = A_hat t2 + b2 ; sq = |emb|^2 ----------
__global__ __launch_bounds__(256) void layer2_kernel(const float* __restrict__ t2,
    const int* __restrict__ row_ptr, const int* __restrict__ srcs,
    const float* __restrict__ norms, const float* __restrict__ dinv,
    const float* __restrict__ b2, float* __restrict__ emb, float* __restrict__ sq) {
  int wid = threadIdx.x >> 6;
  int lane = threadIdx.x & 63;
  int i = blockIdx.x * 4 + wid;
  float di = dinv[i];
  int beg = row_ptr[i], end = row_ptr[i + 1];
  float a0 = 0.f, a1 = 0.f;
  for (int e = beg + lane; e < end; e += 64) {
    int s = srcs[e];
    float ns = norms[e];
    a0 += ns * t2[2 * s + 0];
    a1 += ns * t2[2 * s + 1];
  }
#pragma unroll
  for (int off = 32; off > 0; off >>= 1) {
    a0 += __shfl_down(a0, off, 64);
    a1 += __shfl_down(a1, off, 64);
  }
  if (lane == 0) {
    float e0 = di * a0 + di * di * t2[2 * i + 0] + b2[0];
    float e1 = di * a1 + di * di * t2[2 * i + 1] + b2[1];
    emb[2 * i + 0] = e0;
    emb[2 * i + 1] = e1;
    sq[i] = e0 * e0 + e1 * e1;
  }
}

// ---------- q matrix: q[i][j] = 1/(1 + alpha * d2^beta) ----------
__global__ __launch_bounds__(256) void q_kernel(const float* __restrict__ emb,
    const float* __restrict__ sq, float* __restrict__ q) {
  int t = threadIdx.x;
  int j0 = blockIdx.x * 1024 + t * 4;
  int i0 = blockIdx.y * 32;
  float ex[4], ey[4], sj[4];
#pragma unroll
  for (int jj = 0; jj < 4; ++jj) {
    ex[jj] = emb[2 * (j0 + jj) + 0];
    ey[jj] = emb[2 * (j0 + jj) + 1];
    sj[jj] = sq[j0 + jj];
  }
  for (int ii = 0; ii < 32; ++ii) {
    int i = i0 + ii;
    float xi = emb[2 * i + 0], yi = emb[2 * i + 1], si = sq[i];
    float out4[4];
#pragma unroll
    for (int jj = 0; jj < 4; ++jj) {
      float d2 = si + sj[jj] - 2.f * (xi * ex[jj] + yi * ey[jj]);
      d2 = fmaxf(d2, 0.f);
      float pw = __expf(BETAC * __logf(d2));         // d2^beta
      float den = fmaf(ALPHAC, pw, 1.f);
      float qv = __builtin_amdgcn_rcpf(den);         // den >= 1, ~1 ulp
      out4[jj] = (d2 > 0.f) ? qv : 1.f;
    }
    floatx4 r = {out4[0], out4[1], out4[2], out4[3]};
    __builtin_nontemporal_store(r, (floatx4*)&q[(size_t)i * NN + j0]);
  }
}

extern "C" void kernel_launch(void* const* d_in, const int* in_sizes, int n_in,
                              void* d_out, int out_size, void* d_ws, size_t ws_size,
                              hipStream_t stream) {
  const float* features = (const float*)d_in[0];
  const int* edge_index = (const int*)d_in[1];
  const float* W1 = (const float*)d_in[2];
  const float* b1 = (const float*)d_in[3];
  const float* W2 = (const float*)d_in[4];
  const float* b2 = (const float*)d_in[5];
  float* out = (float*)d_out;

  const int* src = edge_index;       // edge_index[0]
  const int* dst = edge_index + EE;  // edge_index[1]

  // workspace layout (~10.7 MB)
  int* cnt = (int*)d_ws;                 // NN
  int* row_ptr = cnt + NN;               // NN+1 (padded to 8448)
  int* cursor = row_ptr + 8448;          // NN
  int* srcs = cursor + NN;               // EE
  float* norms = (float*)(srcs + EE);    // EE
  float* dinv = norms + EE;              // NN
  float* sqv = dinv + NN;                // NN
  float* t2 = sqv + NN;                  // 2*NN
  float* t1 = t2 + 2 * NN;               // NN*HH

  float* emb = out;              // [NN,2]
  float* qout = out + 2 * NN;    // [NN,NN]

  zero_cnt_kernel<<<NN / 256, 256, 0, stream>>>(cnt);
  count_edges_kernel<<<EE / 256, 256, 0, stream>>>(dst, cnt);
  scan_build_kernel<<<1, 256, 0, stream>>>(cnt, row_ptr, cursor, dinv);
  scatter_edges_kernel<<<EE / 256, 256, 0, stream>>>(src, dst, cursor, dinv, srcs, norms);
  gemm1_kernel<<<dim3(HH / BN, NN / BM), 256, 0, stream>>>(features, W1, t1);
  layer1_kernel<<<NN / 4, 256, 0, stream>>>(t1, row_ptr, srcs, norms, dinv, b1, W2, t2);
  layer2_kernel<<<NN / 4, 256, 0, stream>>>(t2, row_ptr, srcs, norms, dinv, b2, emb, sqv);
  q_kernel<<<dim3(NN / 1024, NN / 32), 256, 0, stream>>>(emb, sqv, qout);
}